// Round 8
// baseline (2701.256 us; speedup 1.0000x reference)
//
#include <hip/hip_runtime.h>
#include <hip/hip_bf16.h>

typedef _Float16 f16;
typedef _Float16 half8 __attribute__((ext_vector_type(8)));
typedef _Float16 half2_ __attribute__((ext_vector_type(2)));
typedef float float4_ __attribute__((ext_vector_type(4)));

#define BB   256
#define SS   128
#define HH   512
#define IN_  414
#define INP  416
#define NN   207
#define OUT_ 414

// flags: per-producer monotonic step counters, COMPACT 4B slots.
// layout: int stamps[2 layers][4 bb-groups][64 producers] = 2 KB (pad 4 KB).
// Poll = one coalesced 64-lane load over 256 contiguous bytes (2-4 fabric
// transactions) instead of round-4's 64 x 128B-strided lines (4 KB/poll).
// THE ONLY CHANGE vs the round-4 kernel (single-variable isolation).
#define FLAG_BYTES 4096

// ---------------------------------------------------------------------------
// x [B,414,S] fp32 -> xpad [S][B][416] fp16 (cols 414,415 zero), LDS-tiled.
// ---------------------------------------------------------------------------
__global__ __launch_bounds__(256) void transpose_pad_x_fp16(
    const float* __restrict__ x, f16* __restrict__ xp)
{
    __shared__ float T[64][130];
    const int tid = threadIdx.x;
    const int b  = blockIdx.x;
    const int i0 = blockIdx.y * 64;
#pragma unroll
    for (int it = 0; it < 32; ++it) {
        int idx = it * 256 + tid;
        int ii = idx >> 7, s = idx & 127;
        int i = i0 + ii;
        T[ii][s] = (i < IN_) ? x[((size_t)b * IN_ + i) * SS + s] : 0.f;
    }
    __syncthreads();
#pragma unroll
    for (int it = 0; it < 32; ++it) {
        int idx = it * 256 + tid;
        int ii = idx & 63, s = idx >> 6;
        int i = i0 + ii;
        if (i < INP) xp[((size_t)s * BB + b) * INP + i] = (f16)T[ii][s];
    }
}

// ---------------------------------------------------------------------------
// Sync protocol — ZERO fences (round-4-proven):
//  - h writes are global_atomic_pk_add_f16 into ZEROED buffers. Agent-scope
//    RMW atomics execute at the device coherence point (MALL): no dirty L2
//    lines anywhere, no release fence needed.
//  - producer: s_waitcnt vmcnt(0) (no-return atomics ack on execution at the
//    coherence point) -> __syncthreads -> thread 0 fetch_add on its own 4B
//    stamp slot.
//  - consumer: wave 0 polls all 64 slots with ONE coalesced 64-lane relaxed
//    agent load; exit when __all(slot >= target). No acquire fence needed
//    (in-launch single-writer-then-read; consumer cache fills happen
//    post-stamp and are MALL-fresh by construction).
// ---------------------------------------------------------------------------
__device__ __forceinline__ void wait_ge(const int* slots, int target)
{
    if (threadIdx.x < 64) {
        const int* p = slots + threadIdx.x;
        for (;;) {
            int v = __hip_atomic_load(p, __ATOMIC_RELAXED,
                                      __HIP_MEMORY_SCOPE_AGENT);
            if (__all(v >= target)) break;
            __builtin_amdgcn_s_sleep(1);
        }
    }
    __syncthreads();
}

__device__ __forceinline__ void signal_stamp(int* slot)
{
    // all this thread's h-atomics executed at MALL before the barrier
    asm volatile("s_waitcnt vmcnt(0)" ::: "memory");
    __syncthreads();
    if (threadIdx.x == 0)
        __hip_atomic_fetch_add(slot, 1, __ATOMIC_RELAXED,
                               __HIP_MEMORY_SCOPE_AGENT);
}

// h store: pk fp16 atomic-add into zeroed memory -> executes at MALL.
// Inline asm (round-4-proven). No-return form; p4 4-byte aligned.
__device__ __forceinline__ void store_h_pk(f16* p4, half2_ v)
{
    asm volatile("global_atomic_pk_add_f16 %0, %1, off"
                 :: "v"(p4), "v"(v)
                 : "memory");
}

// ---------------------------------------------------------------------------
// MFMA phase: weights (LDS, A/M-operand) x activations (global, B/N-operand).
// Wave tile: 16 weight-cols x 32 activation rows (2 acc chains).
// DEEP PRELOAD: all NCH chunks' A-fragments loaded before the MFMA chain.
// LDS swizzle: element (c,k) at colbase + (k&7) + ((k&~7) ^ ((c&7)<<3)).
// ---------------------------------------------------------------------------
template<int NCH>
__device__ __forceinline__ void mfma_phase(
    const f16* __restrict__ A, int Ks,
    const f16* __restrict__ Wl, int swz,
    int ldsBase, int lane,
    float4_& acc0, float4_& acc1)
{
    const int q8 = 8 * (lane >> 4);
    const f16* Ap  = A + (size_t)(lane & 15) * Ks + q8;
    const f16* Ap2 = Ap + 16 * (size_t)Ks;

    half8 a0[NCH], a1[NCH];
#pragma unroll
    for (int kt = 0; kt < NCH; ++kt) {
        a0[kt] = *(const half8*)(Ap  + 32 * kt);
        a1[kt] = *(const half8*)(Ap2 + 32 * kt);
    }

    const int koff = ldsBase + q8;
#pragma unroll
    for (int kt = 0; kt < NCH; ++kt) {
        half8 wf = *(const half8*)(Wl + ((koff + 32 * kt) ^ swz));
        acc0 = __builtin_amdgcn_mfma_f32_16x16x32_f16(wf, a0[kt], acc0, 0, 0, 0);
        acc1 = __builtin_amdgcn_mfma_f32_16x16x32_f16(wf, a1[kt], acc1, 0, 0, 0);
    }
}

// ---------------------------------------------------------------------------
// Persistent LSTM, stamp-synced. 512 WGs x 256 thr (2 WGs/CU).
// WGs 0..255: layer 0; 256..511: layer 1. Per WG: 64 batches x 8 jj x 4 gates.
// Weight tile (32 cols x 1024 k fp16 = 64 KB) resident in LDS all steps.
// Gate-col order c = 4*jj_local + gate => lane-local epilogue; c-state in regs.
// ---------------------------------------------------------------------------
__global__ __launch_bounds__(256, 2) void lstm_persist_mfma(
    const f16* __restrict__ xpad,     // [S][B][416]
    const float* __restrict__ wih0,   // [2048][414]
    const float* __restrict__ whh0,   // [2048][512]
    const float* __restrict__ bih0, const float* __restrict__ bhh0,
    const float* __restrict__ wih1,   // [2048][512]
    const float* __restrict__ whh1,   // [2048][512]
    const float* __restrict__ bih1, const float* __restrict__ bhh1,
    f16* __restrict__ h1,             // [S][B][512]  (pre-zeroed)
    f16* __restrict__ h2,             // [S][B][512]  (pre-zeroed)
    int* __restrict__ flags)
{
    __shared__ f16 Wlds[32 * 1024];   // 64 KB exactly -- DO NOT EXCEED

    const int tid  = threadIdx.x;
    const int lane = tid & 63;
    const int w    = tid >> 6;
    const int wg   = blockIdx.x;
    const int layer = wg >> 8;
    const int r    = wg & 255;
    const int bb   = (r >> 6) * 64;
    const int bb4  = r >> 6;
    const int p    = r & 63;          // producer id within the group
    const int jj0  = p * 8;

    // ---- stage weights (once): LDS col c <-> weight row j = (c&3)*H + jj0 + (c>>2)
    for (int idx = tid; idx < 32 * 1024; idx += 256) {
        int c = idx >> 10, k = idx & 1023;
        int j = (c & 3) * HH + jj0 + (c >> 2);
        float v;
        if (layer == 0) {
            if (k < IN_)                       v = wih0[(size_t)j * IN_ + k];
            else if (k >= INP && k < INP + HH) v = whh0[(size_t)j * HH + (k - INP)];
            else                               v = 0.f;
        } else {
            v = (k < HH) ? wih1[(size_t)j * HH + k]
                         : whh1[(size_t)j * HH + (k - HH)];
        }
        int sk = (k & 7) | ((k & ~7) ^ ((c & 7) << 3));
        Wlds[(c << 10) + sk] = (f16)v;
    }
    __syncthreads();

    const int c_row = (lane & 15) + 16 * (w & 1);
    const int swz   = (c_row & 7) << 3;
    const f16* Wl   = &Wlds[c_row << 10];
    const int nb    = bb + 32 * (w >> 1);
    const int jj    = jj0 + 4 * (w & 1) + (lane >> 4);
    const int b0    = nb + (lane & 15);
    const int jje   = jj & ~1;
    const int par   = jj & 1;

    const float* bi_p = layer ? bih1 : bih0;
    const float* bh_p = layer ? bhh1 : bhh0;
    float bs[4];
#pragma unroll
    for (int g = 0; g < 4; ++g) bs[g] = bi_p[g * HH + jj] + bh_p[g * HH + jj];

    // stamp slot groups: [layer][bb4][64 producers], compact 4B slots
    int* grp0 = flags + (size_t)(0 * 4 + bb4) * 64;
    int* grp1 = flags + (size_t)(1 * 4 + bb4) * 64;
    int* my_slot = (layer ? grp1 : grp0) + p;

    float c0 = 0.f, c1 = 0.f;

    for (int s = 0; s < SS; ++s) {
        float4_ acc0 = {0.f, 0.f, 0.f, 0.f};
        float4_ acc1 = {0.f, 0.f, 0.f, 0.f};

        if (layer == 0) {
            // x-projection first: no dependency, overlaps producers finishing
            mfma_phase<13>(xpad + (size_t)s * BB * INP + (size_t)nb * INP,
                           INP, Wl, swz, 0, lane, acc0, acc1);
            if (s >= 1) {
                wait_ge(grp0, s);     // h1[s-1] complete (stamp s)
                mfma_phase<16>(h1 + (size_t)(s - 1) * BB * HH + (size_t)nb * HH,
                               HH, Wl, swz, INP, lane, acc0, acc1);
            }
        } else {
            wait_ge(grp0, s + 1);     // h1[s] complete (stamp s+1)
            mfma_phase<16>(h1 + (size_t)s * BB * HH + (size_t)nb * HH,
                           HH, Wl, swz, 0, lane, acc0, acc1);
            if (s >= 1) {
                wait_ge(grp1, s);     // h2[s-1] complete (stamp s)
                mfma_phase<16>(h2 + (size_t)(s - 1) * BB * HH + (size_t)nb * HH,
                               HH, Wl, swz, HH, lane, acc0, acc1);
            }
        }

        f16* hout = (layer ? h2 : h1) + (size_t)s * BB * HH;
        {
            float xi = acc0[0] + bs[0], xf = acc0[1] + bs[1];
            float xg = acc0[2] + bs[2], xo = acc0[3] + bs[3];
            float ig = 1.f / (1.f + __expf(-xi));
            float fg = 1.f / (1.f + __expf(-xf));
            float gg = tanhf(xg);
            float og = 1.f / (1.f + __expf(-xo));
            c0 = fg * c0 + ig * gg;
            float hv = og * tanhf(c0);
            half2_ pv;
            pv[0] = par ? (f16)0.f : (f16)hv;
            pv[1] = par ? (f16)hv  : (f16)0.f;
            store_h_pk(hout + (size_t)b0 * HH + jje, pv);
        }
        {
            float xi = acc1[0] + bs[0], xf = acc1[1] + bs[1];
            float xg = acc1[2] + bs[2], xo = acc1[3] + bs[3];
            float ig = 1.f / (1.f + __expf(-xi));
            float fg = 1.f / (1.f + __expf(-xf));
            float gg = tanhf(xg);
            float og = 1.f / (1.f + __expf(-xo));
            c1 = fg * c1 + ig * gg;
            float hv = og * tanhf(c1);
            half2_ pv;
            pv[0] = par ? (f16)0.f : (f16)hv;
            pv[1] = par ? (f16)hv  : (f16)0.f;
            store_h_pk(hout + (size_t)(b0 + 16) * HH + jje, pv);
        }

        signal_stamp(my_slot);
    }
}

// ---------------------------------------------------------------------------
// FC via MFMA, weights-in-LDS. Grid (256 b, 7 o-blocks).
// WG: 64 o-cols x 512 k fp16 in LDS; wave w owns o-cols 16w..16w+15.
// si=0..3: wave tile 16 o x 32 s. Lanes 0..15 write consecutive s: coalesced.
// h2 read cacheably: kernel dispatch boundary provides visibility (proven).
// ---------------------------------------------------------------------------
__global__ __launch_bounds__(256, 2) void fc_mfma(
    const f16* __restrict__ h2,       // [S*B][512], row m = s*256 + b
    const float* __restrict__ fc_w,   // [414][512]
    const float* __restrict__ fc_b,   // [414]
    float* __restrict__ out)          // [B, 2, 207, 128]
{
    __shared__ f16 W[64 * 512];       // 64 KB

    const int tid = threadIdx.x;
    const int b   = blockIdx.x;
    const int o0  = blockIdx.y * 64;

    for (int idx = tid; idx < 64 * 512; idx += 256) {
        int c = idx >> 9, k = idx & 511;
        int o = o0 + c;
        float v = (o < OUT_) ? fc_w[(size_t)o * HH + k] : 0.f;
        int sk = (k & 7) | ((k & ~7) ^ ((c & 7) << 3));
        W[(c << 9) + sk] = (f16)v;
    }
    __syncthreads();

    const int lane  = tid & 63;
    const int w     = tid >> 6;
    const int c_row = (lane & 15) + 16 * w;
    const int swz   = (c_row & 7) << 3;
    const f16* Wl   = &W[c_row << 9];
    const int RS    = BB * HH;        // h2 row stride between consecutive s

    for (int si = 0; si < 4; ++si) {
        const int s0 = si * 32;
        float4_ acc0 = {0.f, 0.f, 0.f, 0.f};
        float4_ acc1 = {0.f, 0.f, 0.f, 0.f};
        mfma_phase<16>(h2 + (size_t)s0 * RS + (size_t)b * HH,
                       RS, Wl, swz, 0, lane, acc0, acc1);

#pragma unroll
        for (int reg = 0; reg < 4; ++reg) {
            const int o = o0 + 16 * w + (lane >> 4) * 4 + reg;
            if (o < OUT_) {
                const int oc = (o < NN) ? 0 : 1;
                const int n  = (o < NN) ? o : o - NN;
                float* op = out + (((size_t)b * 2 + oc) * NN + n) * SS;
                op[s0 + (lane & 15)]      = acc0[reg] + fc_b[o];
                op[s0 + 16 + (lane & 15)] = acc1[reg] + fc_b[o];
            }
        }
    }
}

// ---------------------------------------------------------------------------
extern "C" void kernel_launch(void* const* d_in, const int* in_sizes, int n_in,
                              void* d_out, int out_size, void* d_ws, size_t ws_size,
                              hipStream_t stream)
{
    const float* x     = (const float*)d_in[0];
    const float* w_ih0 = (const float*)d_in[1];
    const float* w_hh0 = (const float*)d_in[2];
    const float* b_ih0 = (const float*)d_in[3];
    const float* b_hh0 = (const float*)d_in[4];
    const float* w_ih1 = (const float*)d_in[5];
    const float* w_hh1 = (const float*)d_in[6];
    const float* b_ih1 = (const float*)d_in[7];
    const float* b_hh1 = (const float*)d_in[8];
    const float* fc_w  = (const float*)d_in[9];
    const float* fc_b  = (const float*)d_in[10];
    float* out = (float*)d_out;

    char* ws = (char*)d_ws;
    int* flags = (int*)ws;
    f16* xpad  = (f16*)(ws + FLAG_BYTES);
    f16* h1    = (f16*)(ws + FLAG_BYTES + (size_t)SS * BB * INP * 2);
    f16* h2    = (f16*)(ws + FLAG_BYTES + (size_t)SS * BB * INP * 2
                           + (size_t)SS * BB * HH * 2);

    // 0) zero the stamp slots AND h1/h2 (h stores are atomic adds into zero)
    hipMemsetAsync(flags, 0, FLAG_BYTES, stream);
    hipMemsetAsync(h1, 0, (size_t)SS * BB * HH * 2 * 2, stream);  // h1+h2

    // 1) transpose + pad + fp16-cast x
    transpose_pad_x_fp16<<<dim3(BB, 7), 256, 0, stream>>>(x, xpad);

    // 2) persistent MFMA LSTM, stamp-synced, fence-free
    {
        void* args[] = {
            (void*)&xpad, (void*)&w_ih0, (void*)&w_hh0,
            (void*)&b_ih0, (void*)&b_hh0,
            (void*)&w_ih1, (void*)&w_hh1, (void*)&b_ih1, (void*)&b_hh1,
            (void*)&h1, (void*)&h2, (void*)&flags
        };
        hipLaunchCooperativeKernel((void*)lstm_persist_mfma,
                                   dim3(512), dim3(256), args, 0, stream);
    }

    // 3) FC via MFMA + output transpose
    fc_mfma<<<dim3(BB, 7), 256, 0, stream>>>(h2, fc_w, fc_b, out);
}

// Round 9
// 2234.616 us; speedup vs baseline: 1.2088x; 1.2088x over previous
//
#include <hip/hip_runtime.h>
#include <hip/hip_bf16.h>

typedef _Float16 f16;
typedef _Float16 half8 __attribute__((ext_vector_type(8)));
typedef _Float16 half2_ __attribute__((ext_vector_type(2)));
typedef float float4_ __attribute__((ext_vector_type(4)));

#define BB   256
#define SS   128
#define HH   512
#define IN_  414
#define INP  416
#define NN   207
#define OUT_ 414

// flags: per-producer monotonic step counters, compact 4B slots (r8-proven).
// layout: int stamps[2 layers][4 bb-groups][64 producers] = 2 KB (pad 4 KB).
#define FLAG_BYTES 4096

// ---------------------------------------------------------------------------
// x [B,414,S] fp32 -> xpad [S][B][416] fp16 (cols 414,415 zero), LDS-tiled.
// ---------------------------------------------------------------------------
__global__ __launch_bounds__(256) void transpose_pad_x_fp16(
    const float* __restrict__ x, f16* __restrict__ xp)
{
    __shared__ float T[64][130];
    const int tid = threadIdx.x;
    const int b  = blockIdx.x;
    const int i0 = blockIdx.y * 64;
#pragma unroll
    for (int it = 0; it < 32; ++it) {
        int idx = it * 256 + tid;
        int ii = idx >> 7, s = idx & 127;
        int i = i0 + ii;
        T[ii][s] = (i < IN_) ? x[((size_t)b * IN_ + i) * SS + s] : 0.f;
    }
    __syncthreads();
#pragma unroll
    for (int it = 0; it < 32; ++it) {
        int idx = it * 256 + tid;
        int ii = idx & 63, s = idx >> 6;
        int i = i0 + ii;
        if (i < INP) xp[((size_t)s * BB + b) * INP + i] = (f16)T[ii][s];
    }
}

// ---------------------------------------------------------------------------
// Sync protocol — ZERO fences (round-4/8-proven):
//  - h writes are global_atomic_pk_add_f16 into ZEROED buffers. Agent-scope
//    RMW atomics execute at the device coherence point (MALL): no dirty L2
//    lines anywhere, no release fence needed.
//  - producer: s_waitcnt vmcnt(0) (no-return atomics ack on execution at the
//    coherence point) -> __syncthreads -> thread 0 fetch_add on its own 4B
//    stamp slot.
//  - consumer: wave 0 polls all 64 slots with ONE coalesced 64-lane relaxed
//    agent load; exit when __all(slot >= target). No acquire fence needed
//    (in-launch single-writer-then-read; consumer cache fills happen
//    post-stamp and are MALL-fresh by construction).
// R9 CHANGE (single variable vs r8): dense pk commits via one shfl_xor(16) --
// each 4B h-pair gets ONE pk-add with both halves real (256 RMWs/WG/step,
// was 512 with zeroed halves). Attacks the commit-burst drain that sits on
// the stamping path (vmcnt(0) before stamp).
// ---------------------------------------------------------------------------
__device__ __forceinline__ void wait_ge(const int* slots, int target)
{
    if (threadIdx.x < 64) {
        const int* p = slots + threadIdx.x;
        for (;;) {
            int v = __hip_atomic_load(p, __ATOMIC_RELAXED,
                                      __HIP_MEMORY_SCOPE_AGENT);
            if (__all(v >= target)) break;
            __builtin_amdgcn_s_sleep(1);
        }
    }
    __syncthreads();
}

__device__ __forceinline__ void signal_stamp(int* slot)
{
    // all this thread's h-atomics executed at MALL before the barrier
    asm volatile("s_waitcnt vmcnt(0)" ::: "memory");
    __syncthreads();
    if (threadIdx.x == 0)
        __hip_atomic_fetch_add(slot, 1, __ATOMIC_RELAXED,
                               __HIP_MEMORY_SCOPE_AGENT);
}

// h store: pk fp16 atomic-add into zeroed memory -> executes at MALL.
// Inline asm (round-4/8-proven). No-return form; p4 4-byte aligned.
__device__ __forceinline__ void store_h_pk(f16* p4, half2_ v)
{
    asm volatile("global_atomic_pk_add_f16 %0, %1, off"
                 :: "v"(p4), "v"(v)
                 : "memory");
}

// ---------------------------------------------------------------------------
// MFMA phase: weights (LDS, A/M-operand) x activations (global, B/N-operand).
// Wave tile: 16 weight-cols x 32 activation rows (2 acc chains).
// DEEP PRELOAD: all NCH chunks' A-fragments loaded before the MFMA chain.
// LDS swizzle: element (c,k) at colbase + (k&7) + ((k&~7) ^ ((c&7)<<3)).
// ---------------------------------------------------------------------------
template<int NCH>
__device__ __forceinline__ void mfma_phase(
    const f16* __restrict__ A, int Ks,
    const f16* __restrict__ Wl, int swz,
    int ldsBase, int lane,
    float4_& acc0, float4_& acc1)
{
    const int q8 = 8 * (lane >> 4);
    const f16* Ap  = A + (size_t)(lane & 15) * Ks + q8;
    const f16* Ap2 = Ap + 16 * (size_t)Ks;

    half8 a0[NCH], a1[NCH];
#pragma unroll
    for (int kt = 0; kt < NCH; ++kt) {
        a0[kt] = *(const half8*)(Ap  + 32 * kt);
        a1[kt] = *(const half8*)(Ap2 + 32 * kt);
    }

    const int koff = ldsBase + q8;
#pragma unroll
    for (int kt = 0; kt < NCH; ++kt) {
        half8 wf = *(const half8*)(Wl + ((koff + 32 * kt) ^ swz));
        acc0 = __builtin_amdgcn_mfma_f32_16x16x32_f16(wf, a0[kt], acc0, 0, 0, 0);
        acc1 = __builtin_amdgcn_mfma_f32_16x16x32_f16(wf, a1[kt], acc1, 0, 0, 0);
    }
}

// ---------------------------------------------------------------------------
// Persistent LSTM, stamp-synced. 512 WGs x 256 thr (2 WGs/CU).
// WGs 0..255: layer 0; 256..511: layer 1. Per WG: 64 batches x 8 jj x 4 gates.
// Weight tile (32 cols x 1024 k fp16 = 64 KB) resident in LDS all steps.
// Gate-col order c = 4*jj_local + gate => lane-local epilogue; c-state in regs.
// ---------------------------------------------------------------------------
__global__ __launch_bounds__(256, 2) void lstm_persist_mfma(
    const f16* __restrict__ xpad,     // [S][B][416]
    const float* __restrict__ wih0,   // [2048][414]
    const float* __restrict__ whh0,   // [2048][512]
    const float* __restrict__ bih0, const float* __restrict__ bhh0,
    const float* __restrict__ wih1,   // [2048][512]
    const float* __restrict__ whh1,   // [2048][512]
    const float* __restrict__ bih1, const float* __restrict__ bhh1,
    f16* __restrict__ h1,             // [S][B][512]  (pre-zeroed)
    f16* __restrict__ h2,             // [S][B][512]  (pre-zeroed)
    int* __restrict__ flags)
{
    __shared__ f16 Wlds[32 * 1024];   // 64 KB exactly -- DO NOT EXCEED

    const int tid  = threadIdx.x;
    const int lane = tid & 63;
    const int w    = tid >> 6;
    const int wg   = blockIdx.x;
    const int layer = wg >> 8;
    const int r    = wg & 255;
    const int bb   = (r >> 6) * 64;
    const int bb4  = r >> 6;
    const int p    = r & 63;          // producer id within the group
    const int jj0  = p * 8;

    // ---- stage weights (once): LDS col c <-> weight row j = (c&3)*H + jj0 + (c>>2)
    for (int idx = tid; idx < 32 * 1024; idx += 256) {
        int c = idx >> 10, k = idx & 1023;
        int j = (c & 3) * HH + jj0 + (c >> 2);
        float v;
        if (layer == 0) {
            if (k < IN_)                       v = wih0[(size_t)j * IN_ + k];
            else if (k >= INP && k < INP + HH) v = whh0[(size_t)j * HH + (k - INP)];
            else                               v = 0.f;
        } else {
            v = (k < HH) ? wih1[(size_t)j * HH + k]
                         : whh1[(size_t)j * HH + (k - HH)];
        }
        int sk = (k & 7) | ((k & ~7) ^ ((c & 7) << 3));
        Wlds[(c << 10) + sk] = (f16)v;
    }
    __syncthreads();

    const int c_row = (lane & 15) + 16 * (w & 1);
    const int swz   = (c_row & 7) << 3;
    const f16* Wl   = &Wlds[c_row << 10];
    const int nb    = bb + 32 * (w >> 1);
    const int jj    = jj0 + 4 * (w & 1) + (lane >> 4);
    const int b0    = nb + (lane & 15);
    const int jje   = jj & ~1;
    const int qodd  = (lane >> 4) & 1;   // odd quad: owns the acc1-row commit

    const float* bi_p = layer ? bih1 : bih0;
    const float* bh_p = layer ? bhh1 : bhh0;
    float bs[4];
#pragma unroll
    for (int g = 0; g < 4; ++g) bs[g] = bi_p[g * HH + jj] + bh_p[g * HH + jj];

    // stamp slot groups: [layer][bb4][64 producers], compact 4B slots
    int* grp0 = flags + (size_t)(0 * 4 + bb4) * 64;
    int* grp1 = flags + (size_t)(1 * 4 + bb4) * 64;
    int* my_slot = (layer ? grp1 : grp0) + p;

    float c0 = 0.f, c1 = 0.f;

    for (int s = 0; s < SS; ++s) {
        float4_ acc0 = {0.f, 0.f, 0.f, 0.f};
        float4_ acc1 = {0.f, 0.f, 0.f, 0.f};

        if (layer == 0) {
            // x-projection first: no dependency, overlaps producers finishing
            mfma_phase<13>(xpad + (size_t)s * BB * INP + (size_t)nb * INP,
                           INP, Wl, swz, 0, lane, acc0, acc1);
            if (s >= 1) {
                wait_ge(grp0, s);     // h1[s-1] complete (stamp s)
                mfma_phase<16>(h1 + (size_t)(s - 1) * BB * HH + (size_t)nb * HH,
                               HH, Wl, swz, INP, lane, acc0, acc1);
            }
        } else {
            wait_ge(grp0, s + 1);     // h1[s] complete (stamp s+1)
            mfma_phase<16>(h1 + (size_t)s * BB * HH + (size_t)nb * HH,
                           HH, Wl, swz, 0, lane, acc0, acc1);
            if (s >= 1) {
                wait_ge(grp1, s);     // h2[s-1] complete (stamp s)
                mfma_phase<16>(h2 + (size_t)(s - 1) * BB * HH + (size_t)nb * HH,
                               HH, Wl, swz, HH, lane, acc0, acc1);
            }
        }

        f16* hout = (layer ? h2 : h1) + (size_t)s * BB * HH;
        float hv0, hv1;
        {
            float xi = acc0[0] + bs[0], xf = acc0[1] + bs[1];
            float xg = acc0[2] + bs[2], xo = acc0[3] + bs[3];
            float ig = 1.f / (1.f + __expf(-xi));
            float fg = 1.f / (1.f + __expf(-xf));
            float gg = tanhf(xg);
            float og = 1.f / (1.f + __expf(-xo));
            c0 = fg * c0 + ig * gg;
            hv0 = og * tanhf(c0);
        }
        {
            float xi = acc1[0] + bs[0], xf = acc1[1] + bs[1];
            float xg = acc1[2] + bs[2], xo = acc1[3] + bs[3];
            float ig = 1.f / (1.f + __expf(-xi));
            float fg = 1.f / (1.f + __expf(-xf));
            float gg = tanhf(xg);
            float og = 1.f / (1.f + __expf(-xo));
            c1 = fg * c1 + ig * gg;
            hv1 = og * tanhf(c1);
        }

        // R9: dense pair assembly via one xor-16 exchange per row.
        // Lanes L and L+16 hold cols (jje, jje+1) of the same rows.
        // Even quads commit the acc0 row (b0); odd quads the acc1 row (b0+16).
        {
            float o0 = __shfl_xor(hv0, 16);   // partner's acc0 value
            float o1 = __shfl_xor(hv1, 16);   // partner's acc1 value
            half2_ pv;
            f16* dst;
            if (!qodd) {                      // cols (own, partner) = (jje, jje+1)
                pv[0] = (f16)hv0; pv[1] = (f16)o0;
                dst = hout + (size_t)b0 * HH + jje;
            } else {                          // cols (partner, own) = (jje, jje+1)
                pv[0] = (f16)o1;  pv[1] = (f16)hv1;
                dst = hout + (size_t)(b0 + 16) * HH + jje;
            }
            store_h_pk(dst, pv);
        }

        signal_stamp(my_slot);
    }
}

// ---------------------------------------------------------------------------
// FC via MFMA, weights-in-LDS. Grid (256 b, 7 o-blocks).
// WG: 64 o-cols x 512 k fp16 in LDS; wave w owns o-cols 16w..16w+15.
// si=0..3: wave tile 16 o x 32 s. Lanes 0..15 write consecutive s: coalesced.
// h2 read cacheably: kernel dispatch boundary provides visibility (proven).
// ---------------------------------------------------------------------------
__global__ __launch_bounds__(256, 2) void fc_mfma(
    const f16* __restrict__ h2,       // [S*B][512], row m = s*256 + b
    const float* __restrict__ fc_w,   // [414][512]
    const float* __restrict__ fc_b,   // [414]
    float* __restrict__ out)          // [B, 2, 207, 128]
{
    __shared__ f16 W[64 * 512];       // 64 KB

    const int tid = threadIdx.x;
    const int b   = blockIdx.x;
    const int o0  = blockIdx.y * 64;

    for (int idx = tid; idx < 64 * 512; idx += 256) {
        int c = idx >> 9, k = idx & 511;
        int o = o0 + c;
        float v = (o < OUT_) ? fc_w[(size_t)o * HH + k] : 0.f;
        int sk = (k & 7) | ((k & ~7) ^ ((c & 7) << 3));
        W[(c << 9) + sk] = (f16)v;
    }
    __syncthreads();

    const int lane  = tid & 63;
    const int w     = tid >> 6;
    const int c_row = (lane & 15) + 16 * w;
    const int swz   = (c_row & 7) << 3;
    const f16* Wl   = &W[c_row << 9];
    const int RS    = BB * HH;        // h2 row stride between consecutive s

    for (int si = 0; si < 4; ++si) {
        const int s0 = si * 32;
        float4_ acc0 = {0.f, 0.f, 0.f, 0.f};
        float4_ acc1 = {0.f, 0.f, 0.f, 0.f};
        mfma_phase<16>(h2 + (size_t)s0 * RS + (size_t)b * HH,
                       RS, Wl, swz, 0, lane, acc0, acc1);

#pragma unroll
        for (int reg = 0; reg < 4; ++reg) {
            const int o = o0 + 16 * w + (lane >> 4) * 4 + reg;
            if (o < OUT_) {
                const int oc = (o < NN) ? 0 : 1;
                const int n  = (o < NN) ? o : o - NN;
                float* op = out + (((size_t)b * 2 + oc) * NN + n) * SS;
                op[s0 + (lane & 15)]      = acc0[reg] + fc_b[o];
                op[s0 + 16 + (lane & 15)] = acc1[reg] + fc_b[o];
            }
        }
    }
}

// ---------------------------------------------------------------------------
extern "C" void kernel_launch(void* const* d_in, const int* in_sizes, int n_in,
                              void* d_out, int out_size, void* d_ws, size_t ws_size,
                              hipStream_t stream)
{
    const float* x     = (const float*)d_in[0];
    const float* w_ih0 = (const float*)d_in[1];
    const float* w_hh0 = (const float*)d_in[2];
    const float* b_ih0 = (const float*)d_in[3];
    const float* b_hh0 = (const float*)d_in[4];
    const float* w_ih1 = (const float*)d_in[5];
    const float* w_hh1 = (const float*)d_in[6];
    const float* b_ih1 = (const float*)d_in[7];
    const float* b_hh1 = (const float*)d_in[8];
    const float* fc_w  = (const float*)d_in[9];
    const float* fc_b  = (const float*)d_in[10];
    float* out = (float*)d_out;

    char* ws = (char*)d_ws;
    int* flags = (int*)ws;
    f16* xpad  = (f16*)(ws + FLAG_BYTES);
    f16* h1    = (f16*)(ws + FLAG_BYTES + (size_t)SS * BB * INP * 2);
    f16* h2    = (f16*)(ws + FLAG_BYTES + (size_t)SS * BB * INP * 2
                           + (size_t)SS * BB * HH * 2);

    // 0) zero the stamp slots AND h1/h2 (h stores are atomic adds into zero)
    hipMemsetAsync(flags, 0, FLAG_BYTES, stream);
    hipMemsetAsync(h1, 0, (size_t)SS * BB * HH * 2 * 2, stream);  // h1+h2

    // 1) transpose + pad + fp16-cast x
    transpose_pad_x_fp16<<<dim3(BB, 7), 256, 0, stream>>>(x, xpad);

    // 2) persistent MFMA LSTM, stamp-synced, fence-free
    {
        void* args[] = {
            (void*)&xpad, (void*)&w_ih0, (void*)&w_hh0,
            (void*)&b_ih0, (void*)&b_hh0,
            (void*)&w_ih1, (void*)&w_hh1, (void*)&b_ih1, (void*)&b_hh1,
            (void*)&h1, (void*)&h2, (void*)&flags
        };
        hipLaunchCooperativeKernel((void*)lstm_persist_mfma,
                                   dim3(512), dim3(256), args, 0, stream);
    }

    // 3) FC via MFMA + output transpose
    fc_mfma<<<dim3(BB, 7), 256, 0, stream>>>(h2, fc_w, fc_b, out);
}